// Round 6
// baseline (1397.788 us; speedup 1.0000x reference)
//
#include <hip/hip_runtime.h>
#include <math.h>

#define N_NODES 16384
#define N_EDGES 524288
#define D_FEAT  128
#define BATCH   4
#define NPTS    4096   // points per cloud
#define KSEL    2048   // selected per cloud
#define MSEL    (BATCH*KSEL)  // 8192

typedef float f32x2 __attribute__((ext_vector_type(2)));

// packed fp32 ops via asm: guarantees v_pk_* emission AND blocks fma
// contraction (per-half IEEE add/mul identical to scalar reference)
#define PK_ADD(D,A,B) asm("v_pk_add_f32 %0, %1, %2" : "=v"(D) : "v"(A), "v"(B))
#define PK_MUL(D,A,B) asm("v_pk_mul_f32 %0, %1, %2" : "=v"(D) : "v"(A), "v"(B))

#define X8(F) F(0) F(1) F(2) F(3) F(4) F(5) F(6) F(7)

template <int CTRL>
__device__ __forceinline__ unsigned long long dpp_u64(unsigned long long p)
{
    unsigned slo = (unsigned)__builtin_amdgcn_update_dpp(
        0, (int)(unsigned)p, CTRL, 0xf, 0xf, true);
    unsigned shi = (unsigned)__builtin_amdgcn_update_dpp(
        0, (int)(unsigned)(p >> 32), CTRL, 0xf, 0xf, true);
    return (((unsigned long long)shi) << 32) | slo;
}
__device__ __forceinline__ unsigned long long max_u64(unsigned long long a,
                                                      unsigned long long b)
{
    return (b > a) ? b : a;
}

// ---------------------------------------------------------------------------
// FPS: one block per cloud, 256 threads (4 waves), 16 pts/thread as 8 f32x2
// pairs. Packed dist update; per-pair + tree tournament argmax (log-depth,
// no serial chain, first-occurrence tie semantics); single u64 DPP reduce
// (R2's proven tail); query via one ds_read_b128 from interleaved float4.
// ---------------------------------------------------------------------------
__launch_bounds__(256, 1)
__global__ void fps_kernel(const float* __restrict__ pos,
                           int* __restrict__ fp_int,
                           int* __restrict__ inv,
                           float* __restrict__ out_subx,
                           float* __restrict__ out_fp)
{
    __shared__ float4 s4[NPTS];   // 64 KiB: interleaved xyz_ per point
    __shared__ int    sel[KSEL];
    __shared__ unsigned long long pwv[2][4];

    const int b    = blockIdx.x;
    const int tid  = threadIdx.x;
    const int lane = tid & 63;
    const int wv   = tid >> 6;

    const float* gp = pos + (size_t)b * NPTS * 3;
    for (int i = tid; i < NPTS; i += 256) {
        s4[i] = make_float4(gp[3 * i + 0], gp[3 * i + 1], gp[3 * i + 2], 0.0f);
    }
    __syncthreads();

    // pair M holds points j=2M (.x) and j=2M+1 (.y); global li = j*256+tid
#define DECL(M) f32x2 x##M, y##M, z##M, d##M;
    X8(DECL)
#undef DECL
#define LOAD(M) { \
        float4 a = s4[(2*(M))*256 + tid]; \
        float4 c = s4[(2*(M)+1)*256 + tid]; \
        x##M.x = a.x; x##M.y = c.x; \
        y##M.x = a.y; y##M.y = c.y; \
        z##M.x = a.z; z##M.y = c.z; \
        d##M.x = 1e10f; d##M.y = 1e10f; }
    X8(LOAD)
#undef LOAD

    float qx = s4[0].x, qy = s4[0].y, qz = s4[0].z;
    int cur = 0;

    for (int t = 0; t < KSEL; ++t) {
        if (tid == 0) sel[t] = cur;

        // negated splats: x + (-q) == x - q exactly (IEEE)
        f32x2 nqx, nqy, nqz;
        nqx.x = -qx; nqx.y = -qx;
        nqy.x = -qy; nqy.y = -qy;
        nqz.x = -qz; nqz.y = -qz;

        // dist update + per-pair winner (independent across pairs — no chain)
        float pv0,pv1,pv2,pv3,pv4,pv5,pv6,pv7;
        int   pj0,pj1,pj2,pj3,pj4,pj5,pj6,pj7;
#define UPD2(M) { \
        f32x2 dx, dy, dz, mx, my, mz, s1, dd; \
        PK_ADD(dx, x##M, nqx); PK_ADD(dy, y##M, nqy); PK_ADD(dz, z##M, nqz); \
        PK_MUL(mx, dx, dx); PK_MUL(my, dy, dy); PK_MUL(mz, dz, dz); \
        PK_ADD(s1, mx, my); PK_ADD(dd, s1, mz); \
        float n0 = fminf(d##M.x, dd.x); d##M.x = n0; \
        float n1 = fminf(d##M.y, dd.y); d##M.y = n1; \
        pv##M = (n1 > n0) ? n1 : n0; \
        pj##M = (n1 > n0) ? (2*(M)+1) : (2*(M)); }
        X8(UPD2)
#undef UPD2

        // 7-node tree; lower-j operand always in the keep slot (strict >)
#define NODE(VA, JA, VB, JB, VO, JO) \
        float VO = (VB > VA) ? VB : VA; int JO = (VB > VA) ? JB : JA;
        NODE(pv0, pj0, pv1, pj1, tA, jA)  NODE(pv2, pj2, pv3, pj3, tB, jB)
        NODE(pv4, pj4, pv5, pj5, tC, jC)  NODE(pv6, pj6, pv7, pj7, tD, jD)
        NODE(tA, jA, tB, jB, tE, jE)      NODE(tC, jC, tD, jD, tF, jF)
        NODE(tE, jE, tF, jF, bv, bj)
#undef NODE
        int bi = (bj << 8) + tid;  // bj*256 + tid

        // pack (value bits << 32) | ~idx : nonneg float bits order-preserving
        // as unsigned; tie -> larger ~idx -> smaller idx (first occurrence)
        unsigned long long p =
            (((unsigned long long)__float_as_uint(bv)) << 32) |
            (unsigned)(~bi);

        // intra-wave u64 max reduce into lane 63
        p = max_u64(p, dpp_u64<0x111>(p));  // row_shr:1
        p = max_u64(p, dpp_u64<0x112>(p));  // row_shr:2
        p = max_u64(p, dpp_u64<0x114>(p));  // row_shr:4
        p = max_u64(p, dpp_u64<0x118>(p));  // row_shr:8
        p = max_u64(p, dpp_u64<0x142>(p));  // row_bcast:15
        p = max_u64(p, dpp_u64<0x143>(p));  // row_bcast:31

        int par = t & 1;
        if (lane == 63) pwv[par][wv] = p;
        __syncthreads();

        unsigned long long c0 = pwv[par][0];
        unsigned long long c1 = pwv[par][1];
        unsigned long long c2 = pwv[par][2];
        unsigned long long c3 = pwv[par][3];
        unsigned long long m01 = (c1 > c0) ? c1 : c0;
        unsigned long long m23 = (c3 > c2) ? c3 : c2;
        unsigned long long mm  = (m23 > m01) ? m23 : m01;
        cur = (int)(~(unsigned)(mm & 0xffffffffULL));

        float4 q = s4[cur];       // single b128 broadcast read
        qx = q.x; qy = q.y; qz = q.z;
    }
    __syncthreads();

    for (int t = tid; t < KSEL; t += 256) {
        int c = sel[t];
        float4 q = s4[c];
        int g = b * NPTS + c;
        int m = b * KSEL + t;
        fp_int[m] = g;
        inv[g] = m;
        out_fp[m] = (float)g;
        out_subx[m * 3 + 0] = q.x;
        out_subx[m * 3 + 1] = q.y;
        out_subx[m * 3 + 2] = q.z;
    }
}

// ---------------- in-degree histogram ------------------------------------
__global__ void deg_kernel(const int* __restrict__ dst, int* __restrict__ deg)
{
    int e = blockIdx.x * blockDim.x + threadIdx.x;
    if (e < N_EDGES) atomicAdd(&deg[dst[e]], 1);
}

// ---------------- exclusive scan over deg -> row_ptr (single block) ------
__global__ void scan_kernel(const int* __restrict__ deg, int* __restrict__ row_ptr)
{
    __shared__ int part[1024];
    int tid = threadIdx.x;
    int base = tid * 16;
    int local[16];
    int s = 0;
#pragma unroll
    for (int j = 0; j < 16; ++j) { local[j] = s; s += deg[base + j]; }
    part[tid] = s;
    __syncthreads();
    for (int off = 1; off < 1024; off <<= 1) {
        int v = part[tid];
        int add = (tid >= off) ? part[tid - off] : 0;
        __syncthreads();
        part[tid] = v + add;
        __syncthreads();
    }
    int prefix = (tid == 0) ? 0 : part[tid - 1];
#pragma unroll
    for (int j = 0; j < 16; ++j) row_ptr[base + j] = prefix + local[j];
    if (tid == 1023) row_ptr[N_NODES] = part[1023];
}

// ---------------- CSR scatter ---------------------------------------------
__global__ void scatter_kernel(const int* __restrict__ src, const int* __restrict__ dst,
                               const int* __restrict__ row_ptr, int* __restrict__ cursor,
                               int* __restrict__ col)
{
    int e = blockIdx.x * blockDim.x + threadIdx.x;
    if (e < N_EDGES) {
        int d0 = dst[e];
        int r = atomicAdd(&cursor[d0], 1);
        col[row_ptr[d0] + r] = src[e];
    }
}

// ---------------- fused agg (blocks 0..2047) + edge (blocks 2048..4095) ---
__global__ void agg_edge_kernel(const float* __restrict__ feat,
                                const int* __restrict__ fp_int,
                                const int* __restrict__ row_ptr,
                                const int* __restrict__ col,
                                const int* __restrict__ deg,
                                float* __restrict__ out_subfeat,
                                const int* __restrict__ src,
                                const int* __restrict__ dst,
                                const int* __restrict__ inv,
                                const float* __restrict__ subx,
                                float* __restrict__ outd,
                                float* __restrict__ outw,
                                float* __restrict__ outm)
{
    if (blockIdx.x < 2048) {
        int wid  = (blockIdx.x * blockDim.x + threadIdx.x) >> 6;
        int lane = threadIdx.x & 63;
        int v  = fp_int[wid];
        int s0 = row_ptr[v];
        int s1 = row_ptr[v + 1];
        float a0 = 0.0f, a1 = 0.0f;
        for (int e = s0; e < s1; ++e) {
            int s = col[e];
            const float2* f2 = (const float2*)(feat + (size_t)s * D_FEAT);
            float2 vv = f2[lane];
            a0 += vv.x;
            a1 += vv.y;
        }
        float dv = fmaxf((float)deg[v], 1.0f);
        float* o = out_subfeat + (size_t)wid * D_FEAT + lane * 2;
        o[0] = a0 / dv;
        o[1] = a1 / dv;
    } else {
        int e = (blockIdx.x - 2048) * blockDim.x + threadIdx.x;
        int ls = inv[src[e]];
        int ld = inv[dst[e]];
        bool mk = (ls >= 0) && (ld >= 0);
        float dx = 0.0f, dy = 0.0f, dz = 0.0f;
        if (mk) {
            dx = __fsub_rn(subx[ld * 3 + 0], subx[ls * 3 + 0]);
            dy = __fsub_rn(subx[ld * 3 + 1], subx[ls * 3 + 1]);
            dz = __fsub_rn(subx[ld * 3 + 2], subx[ls * 3 + 2]);
        }
        float w = sqrtf(__fadd_rn(__fadd_rn(__fmul_rn(dx, dx), __fmul_rn(dy, dy)),
                                  __fmul_rn(dz, dz)));
        outd[e * 3 + 0] = dx;
        outd[e * 3 + 1] = dy;
        outd[e * 3 + 2] = dz;
        outw[e] = w;
        outm[e] = mk ? 1.0f : 0.0f;
    }
}

// ---------------- launch ---------------------------------------------------
extern "C" void kernel_launch(void* const* d_in, const int* in_sizes, int n_in,
                              void* d_out, int out_size, void* d_ws, size_t ws_size,
                              hipStream_t stream)
{
    const float* pos  = (const float*)d_in[0];   // [16384,3]
    const float* feat = (const float*)d_in[1];   // [16384,128]
    const int*   src  = (const int*)d_in[2];     // [524288]
    const int*   dst  = (const int*)d_in[3];     // [524288]

    float* out = (float*)d_out;
    float* out_subx    = out;                                 // [8192,3]
    float* out_subfeat = out_subx + (size_t)MSEL * 3;         // [8192,128]
    float* out_d       = out_subfeat + (size_t)MSEL * D_FEAT; // [524288,3]
    float* out_w       = out_d + (size_t)N_EDGES * 3;         // [524288]
    float* out_m       = out_w + (size_t)N_EDGES;             // [524288]
    float* out_fp      = out_m + (size_t)N_EDGES;             // [8192]

    int* fp_int  = (int*)d_ws;            // 8192
    int* inv     = fp_int + MSEL;         // 16384
    int* deg     = inv + N_NODES;         // 16384
    int* row_ptr = deg + N_NODES;         // 16385
    int* cursor  = row_ptr + (N_NODES+1); // 16384
    int* col     = cursor + N_NODES;      // 524288

    (void)hipMemsetAsync(inv,    0xFF, (size_t)N_NODES * 4, stream);
    (void)hipMemsetAsync(deg,    0,    (size_t)N_NODES * 4, stream);
    (void)hipMemsetAsync(cursor, 0,    (size_t)N_NODES * 4, stream);

    deg_kernel<<<N_EDGES / 256, 256, 0, stream>>>(dst, deg);
    scan_kernel<<<1, 1024, 0, stream>>>(deg, row_ptr);
    scatter_kernel<<<N_EDGES / 256, 256, 0, stream>>>(src, dst, row_ptr, cursor, col);

    fps_kernel<<<BATCH, 256, 0, stream>>>(pos, fp_int, inv, out_subx, out_fp);

    agg_edge_kernel<<<4096, 256, 0, stream>>>(feat, fp_int, row_ptr, col, deg,
                                              out_subfeat, src, dst, inv, out_subx,
                                              out_d, out_w, out_m);
}

// Round 7
// 1263.161 us; speedup vs baseline: 1.1066x; 1.1066x over previous
//
#include <hip/hip_runtime.h>
#include <math.h>

#define N_NODES 16384
#define N_EDGES 524288
#define D_FEAT  128
#define BATCH   4
#define NPTS    4096   // points per cloud
#define KSEL    2048   // selected per cloud
#define MSEL    (BATCH*KSEL)  // 8192

#define X16(F) F(0) F(1) F(2) F(3) F(4) F(5) F(6) F(7) \
               F(8) F(9) F(10) F(11) F(12) F(13) F(14) F(15)

// ---------------------------------------------------------------------------
// FPS: exact replica of the best-measured variant (1106 us): one block per
// cloud, 256 threads (4 waves), 16 pts/thread in named scalar registers,
// serial argmax interleaved with the dist update (latency-hidden under the
// independent dist ops), single u64 packed DPP reduce, cross-wave via LDS
// packed u64 (val<<32 | ~idx) with parity double-buffer (1 barrier/step).
// Measured variants that REGRESSED vs this: pk-asm packed math (+100us),
// tournament-tree argmax (+20-60us), two-phase f32/u32 reduce (+160us),
// float4-interleaved query read (+worse). Do not reintroduce without
// counter evidence.
// ---------------------------------------------------------------------------

__device__ __forceinline__ unsigned long long dpp_max_step(unsigned long long p,
                                                           unsigned int slo,
                                                           unsigned int shi)
{
    unsigned long long s = (((unsigned long long)shi) << 32) | slo;
    return (s > p) ? s : p;
}

__launch_bounds__(256, 1)
__global__ void fps_kernel(const float* __restrict__ pos,
                           int* __restrict__ fp_int,
                           int* __restrict__ inv,
                           float* __restrict__ out_subx,
                           float* __restrict__ out_fp)
{
    __shared__ float sx[NPTS];
    __shared__ float sy[NPTS];
    __shared__ float sz[NPTS];
    __shared__ int   sel[KSEL];
    __shared__ unsigned long long pwv[2][4];

    const int b   = blockIdx.x;
    const int tid = threadIdx.x;

    const float* gp = pos + (size_t)b * NPTS * 3;
    for (int i = tid; i < NPTS; i += 256) {
        sx[i] = gp[3 * i + 0];
        sy[i] = gp[3 * i + 1];
        sz[i] = gp[3 * i + 2];
    }
    __syncthreads();

#define DECL(J) float x##J, y##J, z##J, d##J;
    X16(DECL)
#undef DECL
#define LOAD(J) { int li = (J)*256 + tid; x##J = sx[li]; y##J = sy[li]; z##J = sz[li]; d##J = 1e10f; }
    X16(LOAD)
#undef LOAD

    int cur = 0;
    for (int t = 0; t < KSEL; ++t) {
        if (tid == 0) sel[t] = cur;
        float qx = sx[cur];
        float qy = sy[cur];
        float qz = sz[cur];

        float bv = -1.0f;
        int   bi = 0x7fffffff;
        // exact reference arithmetic: (dx*dx + dy*dy) + dz*dz, no fma; fminf;
        // strict > keeps smallest index on ties (j ascending = idx ascending)
#define UPD(J) { \
        float dx = __fsub_rn(x##J, qx); \
        float dy = __fsub_rn(y##J, qy); \
        float dz = __fsub_rn(z##J, qz); \
        float dd = __fadd_rn(__fadd_rn(__fmul_rn(dx, dx), __fmul_rn(dy, dy)), \
                             __fmul_rn(dz, dz)); \
        d##J = fminf(d##J, dd); \
        if (d##J > bv) { bv = d##J; bi = (J)*256 + tid; } }
        X16(UPD)
#undef UPD

        // pack: nonneg float bits are order-preserving as unsigned;
        // tie -> larger ~idx -> smaller idx (matches argmax first-occurrence)
        unsigned long long p =
            (((unsigned long long)__float_as_uint(bv)) << 32) |
            (unsigned int)(~bi);

        // DPP wave-64 max reduce into lane 63
        {
            unsigned int lo, hi, slo, shi;
#define DSTEP(CTRL) \
            lo = (unsigned int)p; hi = (unsigned int)(p >> 32); \
            slo = __builtin_amdgcn_update_dpp(0, (int)lo, CTRL, 0xf, 0xf, true); \
            shi = __builtin_amdgcn_update_dpp(0, (int)hi, CTRL, 0xf, 0xf, true); \
            p = dpp_max_step(p, slo, shi);
            DSTEP(0x111)  // row_shr:1
            DSTEP(0x112)  // row_shr:2
            DSTEP(0x114)  // row_shr:4
            DSTEP(0x118)  // row_shr:8
            DSTEP(0x142)  // row_bcast:15
            DSTEP(0x143)  // row_bcast:31
#undef DSTEP
        }

        int par = t & 1;
        if ((tid & 63) == 63) pwv[par][tid >> 6] = p;
        __syncthreads();

        unsigned long long c0 = pwv[par][0];
        unsigned long long c1 = pwv[par][1];
        unsigned long long c2 = pwv[par][2];
        unsigned long long c3 = pwv[par][3];
        unsigned long long m01 = (c0 > c1) ? c0 : c1;
        unsigned long long m23 = (c2 > c3) ? c2 : c3;
        unsigned long long mm  = (m01 > m23) ? m01 : m23;
        cur = (int)(~(unsigned int)(mm & 0xffffffffULL));
    }
    __syncthreads();

    // epilogue: write selections in parallel, coalesced
    for (int t = tid; t < KSEL; t += 256) {
        int c = sel[t];
        int g = b * NPTS + c;
        int m = b * KSEL + t;
        fp_int[m] = g;
        inv[g] = m;
        out_fp[m] = (float)g;
        out_subx[m * 3 + 0] = sx[c];
        out_subx[m * 3 + 1] = sy[c];
        out_subx[m * 3 + 2] = sz[c];
    }
}

// ---------------- in-degree histogram + inv init --------------------------
// inv init folded in (inv is not otherwise touched until fps, which runs
// after this kernel completes on the same stream) — kills one memset.
__global__ void deg_kernel(const int* __restrict__ dst, int* __restrict__ deg,
                           int* __restrict__ inv)
{
    int e = blockIdx.x * blockDim.x + threadIdx.x;
    if (e < N_NODES) inv[e] = -1;
    if (e < N_EDGES) atomicAdd(&deg[dst[e]], 1);
}

// ---------------- exclusive scan over deg -> row_ptr (+ cursor copy) ------
__global__ void scan_kernel(const int* __restrict__ deg, int* __restrict__ row_ptr,
                            int* __restrict__ row_ptr2)
{
    __shared__ int part[1024];
    int tid = threadIdx.x;
    int base = tid * 16;
    int local[16];
    int s = 0;
#pragma unroll
    for (int j = 0; j < 16; ++j) { local[j] = s; s += deg[base + j]; }
    part[tid] = s;
    __syncthreads();
    for (int off = 1; off < 1024; off <<= 1) {
        int v = part[tid];
        int add = (tid >= off) ? part[tid - off] : 0;
        __syncthreads();
        part[tid] = v + add;
        __syncthreads();
    }
    int prefix = (tid == 0) ? 0 : part[tid - 1];
#pragma unroll
    for (int j = 0; j < 16; ++j) {
        int v = prefix + local[j];
        row_ptr[base + j]  = v;
        row_ptr2[base + j] = v;   // consumed (destroyed) by scatter as cursor
    }
    if (tid == 1023) row_ptr[N_NODES] = part[1023];
}

// ---------------- CSR scatter (row_ptr2 doubles as cursor) ----------------
__global__ void scatter_kernel(const int* __restrict__ src, const int* __restrict__ dst,
                               int* __restrict__ row_ptr2, int* __restrict__ col)
{
    int e = blockIdx.x * blockDim.x + threadIdx.x;
    if (e < N_EDGES) {
        int r = atomicAdd(&row_ptr2[dst[e]], 1);  // returns absolute slot
        col[r] = src[e];
    }
}

// ---------------- fused agg (blocks 0..2047) + edge (blocks 2048..4095) ---
__global__ void agg_edge_kernel(const float* __restrict__ feat,
                                const int* __restrict__ fp_int,
                                const int* __restrict__ row_ptr,
                                const int* __restrict__ col,
                                const int* __restrict__ deg,
                                float* __restrict__ out_subfeat,
                                const int* __restrict__ src,
                                const int* __restrict__ dst,
                                const int* __restrict__ inv,
                                const float* __restrict__ subx,
                                float* __restrict__ outd,
                                float* __restrict__ outw,
                                float* __restrict__ outm)
{
    if (blockIdx.x < 2048) {
        // mean aggregation: one wave per sampled node, lane = 2 feature cols
        int wid  = (blockIdx.x * blockDim.x + threadIdx.x) >> 6;
        int lane = threadIdx.x & 63;
        int v  = fp_int[wid];
        int s0 = row_ptr[v];
        int s1 = row_ptr[v + 1];
        float a0 = 0.0f, a1 = 0.0f;
        for (int e = s0; e < s1; ++e) {
            int s = col[e];
            const float2* f2 = (const float2*)(feat + (size_t)s * D_FEAT);
            float2 vv = f2[lane];
            a0 += vv.x;
            a1 += vv.y;
        }
        float dv = fmaxf((float)deg[v], 1.0f);
        float* o = out_subfeat + (size_t)wid * D_FEAT + lane * 2;
        o[0] = a0 / dv;
        o[1] = a1 / dv;
    } else {
        int e = (blockIdx.x - 2048) * blockDim.x + threadIdx.x;
        int ls = inv[src[e]];
        int ld = inv[dst[e]];
        bool mk = (ls >= 0) && (ld >= 0);
        float dx = 0.0f, dy = 0.0f, dz = 0.0f;
        if (mk) {
            dx = __fsub_rn(subx[ld * 3 + 0], subx[ls * 3 + 0]);
            dy = __fsub_rn(subx[ld * 3 + 1], subx[ls * 3 + 1]);
            dz = __fsub_rn(subx[ld * 3 + 2], subx[ls * 3 + 2]);
        }
        float w = sqrtf(__fadd_rn(__fadd_rn(__fmul_rn(dx, dx), __fmul_rn(dy, dy)),
                                  __fmul_rn(dz, dz)));
        outd[e * 3 + 0] = dx;
        outd[e * 3 + 1] = dy;
        outd[e * 3 + 2] = dz;
        outw[e] = w;
        outm[e] = mk ? 1.0f : 0.0f;
    }
}

// ---------------- launch ---------------------------------------------------
extern "C" void kernel_launch(void* const* d_in, const int* in_sizes, int n_in,
                              void* d_out, int out_size, void* d_ws, size_t ws_size,
                              hipStream_t stream)
{
    const float* pos  = (const float*)d_in[0];   // [16384,3]
    const float* feat = (const float*)d_in[1];   // [16384,128]
    const int*   src  = (const int*)d_in[2];     // [524288]
    const int*   dst  = (const int*)d_in[3];     // [524288]

    float* out = (float*)d_out;
    float* out_subx    = out;                                 // [8192,3]
    float* out_subfeat = out_subx + (size_t)MSEL * 3;         // [8192,128]
    float* out_d       = out_subfeat + (size_t)MSEL * D_FEAT; // [524288,3]
    float* out_w       = out_d + (size_t)N_EDGES * 3;         // [524288]
    float* out_m       = out_w + (size_t)N_EDGES;             // [524288]
    float* out_fp      = out_m + (size_t)N_EDGES;             // [8192]

    int* fp_int   = (int*)d_ws;               // 8192
    int* inv      = fp_int + MSEL;            // 16384
    int* deg      = inv + N_NODES;            // 16384
    int* row_ptr  = deg + N_NODES;            // 16385
    int* row_ptr2 = row_ptr + (N_NODES + 1);  // 16385
    int* col      = row_ptr2 + (N_NODES + 1); // 524288

    (void)hipMemsetAsync(deg, 0, (size_t)N_NODES * 4, stream);

    deg_kernel<<<N_EDGES / 256, 256, 0, stream>>>(dst, deg, inv);
    scan_kernel<<<1, 1024, 0, stream>>>(deg, row_ptr, row_ptr2);
    scatter_kernel<<<N_EDGES / 256, 256, 0, stream>>>(src, dst, row_ptr2, col);

    fps_kernel<<<BATCH, 256, 0, stream>>>(pos, fp_int, inv, out_subx, out_fp);

    agg_edge_kernel<<<4096, 256, 0, stream>>>(feat, fp_int, row_ptr, col, deg,
                                              out_subfeat, src, dst, inv, out_subx,
                                              out_d, out_w, out_m);
}